// Round 2
// 135.342 us; speedup vs baseline: 1.0034x; 1.0034x over previous
//
#include <hip/hip_runtime.h>
#include <hip/hip_bf16.h>
#include <stdint.h>

#define B_ 4
#define S_ 1024
#define E_ 8
#define DE_ 128
#define SCALE_ 0.03125f   // 1/sqrt(1024)

typedef __attribute__((ext_vector_type(8))) short short8;
typedef __attribute__((ext_vector_type(4))) float f32x4;
typedef unsigned short ushort_t;
typedef unsigned int uint32;
typedef unsigned long long u64;
typedef unsigned char uchar;

__device__ __forceinline__ ushort_t f2bf(float f) {
    uint32 u = __float_as_uint(f);
    uint32 r = u + 0x7fffu + ((u >> 16) & 1u);
    return (ushort_t)(r >> 16);
}

// fp32 -> fp8 e4m3fn, RNE, saturating. Manual (no header dependency).
__device__ __forceinline__ uchar f2fp8(float f) {
    float a = fminf(fmaxf(f, -448.f), 448.f);
    uint32 u = __float_as_uint(a);
    uint32 s = (u >> 31) << 7;
    int ex = (int)((u >> 23) & 0xff);
    uint32 man = u & 0x7fffff;
    int e8 = ex - 127 + 7;
    if (e8 >= 1) {
        uint32 m = man >> 20;
        uint32 rem = man & 0xfffff;
        if (rem > 0x80000u || (rem == 0x80000u && (m & 1))) ++m;
        if (m == 8) { m = 0; ++e8; }
        if (e8 > 15) { e8 = 15; m = 6; }          // saturate to 448
        return (uchar)(s | ((uint32)e8 << 3) | m);
    } else {
        int m = (int)rintf(fabsf(a) * 512.f);     // subnormal units 2^-9
        if (m > 7) m = 7;
        return (uchar)(s | (uint32)m);
    }
}

// Async global->LDS DMA. LDS dst = wave-uniform base + lane*size.
#define GLOAD_LDS16(g, l) __builtin_amdgcn_global_load_lds( \
    (const __attribute__((address_space(1))) unsigned int*)(g), \
    (__attribute__((address_space(3))) unsigned int*)(l), 16, 0, 0)
#define GLOAD_LDS4(g, l) __builtin_amdgcn_global_load_lds( \
    (const __attribute__((address_space(1))) unsigned int*)(g), \
    (__attribute__((address_space(3))) unsigned int*)(l), 4, 0, 0)

// --- staging (512-thread blocks). Swizzle: 16B chunk c of row r stored at
// physical slot (c&~7)|((c&7)^(r&7)). DMA fetches logical chunk for slot u.
// K/Q fp8 tiles: rowBytes=128 (8 chunks). V bf16 tiles: rowBytes=256 (16).
// Every stage helper issues a WAVE-UNIFORM number of VMEM instructions
// (required for counted s_waitcnt vmcnt(N) pipelining):
//   stageK32 / stageV32: 4 per thread.  stageQ4: 1 per thread.
__device__ __forceinline__ void stageK32(const uchar* g, uchar* lds, int tid) {
    // 256 rows x 128B contiguous (32 KB)
    #pragma unroll
    for (int k2 = 0; k2 < 4; ++k2) {
        int u = tid + k2 * 512;
        int r = u >> 3, c = u & 7;
        int cc = c ^ (r & 7);
        GLOAD_LDS16(g + r * 128 + (cc << 4), lds + (u << 4));
    }
}
__device__ __forceinline__ void stageV32(const uchar* g, uchar* lds, int tid) {
    // 128 rows x 256B, row stride 2048B (32 KB)
    #pragma unroll
    for (int k2 = 0; k2 < 4; ++k2) {
        int u = tid + k2 * 512;
        int r = u >> 4, c = u & 15;
        int cc = (c & 8) | ((c & 7) ^ (r & 7));
        GLOAD_LDS16(g + (size_t)r * 2048 + (cc << 4), lds + (u << 4));
    }
}
// Q tile 16 rows x 128B (2 KB): 4B per thread, uniform 1 load/thread.
__device__ __forceinline__ void stageQ4(const uchar* g, uchar* lds, int tid) {
    int r = tid >> 5;                 // 32 threads cover one 128B row
    int ct = (tid >> 2) & 7;          // 16B chunk within row
    int bo = (tid & 3) << 2;          // byte offset within chunk
    int cc = ct ^ (r & 7);
    GLOAD_LDS4(g + r * 128 + (cc << 4) + bo, lds + (tid << 2));
}
// fp8 frag read: 8 bytes of row, d-window kk*32 + quad*8
__device__ __forceinline__ u64 fld8(const uchar* lds, int row, int kk, int quad) {
    int c = kk * 2 + (quad >> 1);
    int phys = c ^ (row & 7);
    return *(const u64*)(lds + row * 128 + (phys << 4) + ((quad & 1) << 3));
}
// V bf16 B-frag: 16B of row (d), t-window kk*32 + quad*8 elems
__device__ __forceinline__ short8 fldv(const uchar* lds, int row, int kk, int quad) {
    int c = kk * 4 + quad;
    int phys = (c & 8) | ((c & 7) ^ (row & 7));
    return *(const short8*)(lds + (size_t)row * 256 + (phys << 4));
}

__device__ __forceinline__ void top2(const float* rp, int& i1, int& i2) {
    float v1 = rp[0]; i1 = 0;
    #pragma unroll
    for (int i = 1; i < 8; ++i) { float v = rp[i]; if (v > v1) { v1 = v; i1 = i; } }
    float v2 = -1e30f; i2 = 0;
    #pragma unroll
    for (int i = 0; i < 8; ++i) {
        if (i == i1) continue;
        float v = rp[i]; if (v > v2) { v2 = v; i2 = i; }
    }
}

// ---------------------------------------------------------------------------
// Kernel 1: prep. Q,K fp32 -> fp8 e4m3 [B][E][S][DE] (em-active planes);
// V -> bf16 transposed Vt [B][E][DE][S] (top-2 planes); zero-fill non-top2
// out slices. Grid (16 sc64, 8 e, 4 b), 256 threads.  (unchanged)
// ---------------------------------------------------------------------------
__global__ __launch_bounds__(256) void prep_kernel(
        const float* __restrict__ Q, const float* __restrict__ K,
        const float* __restrict__ V, const float* __restrict__ route,
        const int* __restrict__ em,
        uchar* __restrict__ Qb, uchar* __restrict__ Kb,
        ushort_t* __restrict__ Vt, float* __restrict__ out) {
    __shared__ ushort_t tile[64][130];
    const int tid = threadIdx.x;
    const int sc = blockIdx.x, e = blockIdx.y, b = blockIdx.z;
    const int s0 = sc * 64;
    const size_t plane8 = ((size_t)(b * 8 + e)) << 17;   // bytes (fp8)

    const bool ak = em[e * B_ + b] != 0;
    int i1, i2; top2(route + b * 8, i1, i2);
    const bool av = (e == i1) || (e == i2);

    if (!av) {
        #pragma unroll
        for (int i = 0; i < 8; ++i) {
            int idx = tid + i * 256, r = idx >> 5, c4 = idx & 31;
            *(float4*)(out + (((size_t)(b * 1024 + s0 + r)) << 10) + (e << 7) + (c4 << 2))
                = make_float4(0.f, 0.f, 0.f, 0.f);
        }
    }
    if (ak) {
        #pragma unroll
        for (int i = 0; i < 2; ++i) {
            int u = tid + i * 256;              // 0..511: 16-elem groups
            int r = u >> 3, dg = u & 7;
            const float* qs = Q + ((size_t)(b * 1024 + s0 + r) << 10) + (e << 7) + (dg << 4);
            const float* ks = K + ((size_t)(b * 1024 + s0 + r) << 10) + (e << 7) + (dg << 4);
            union { uint4 w; uchar c[16]; } oq, ok;
            #pragma unroll
            for (int j = 0; j < 4; ++j) {
                float4 qv = ((const float4*)qs)[j];
                float4 kv = ((const float4*)ks)[j];
                oq.c[j*4+0] = f2fp8(qv.x); oq.c[j*4+1] = f2fp8(qv.y);
                oq.c[j*4+2] = f2fp8(qv.z); oq.c[j*4+3] = f2fp8(qv.w);
                ok.c[j*4+0] = f2fp8(kv.x); ok.c[j*4+1] = f2fp8(kv.y);
                ok.c[j*4+2] = f2fp8(kv.z); ok.c[j*4+3] = f2fp8(kv.w);
            }
            size_t oo = plane8 + ((size_t)(s0 + r) << 7) + (dg << 4);
            *(uint4*)(Qb + oo) = oq.w;
            *(uint4*)(Kb + oo) = ok.w;
        }
    }
    if (av) {
        #pragma unroll
        for (int i = 0; i < 8; ++i) {
            int idx = tid + i * 256, r = idx >> 5, c4 = idx & 31;
            size_t in_off = ((size_t)(b * 1024 + s0 + r) << 10) + (e << 7) + (c4 << 2);
            float4 v = *(const float4*)(V + in_off);
            ushort_t* p = &tile[r][c4 << 2];
            p[0] = f2bf(v.x); p[1] = f2bf(v.y); p[2] = f2bf(v.z); p[3] = f2bf(v.w);
        }
        __syncthreads();
        #pragma unroll
        for (int i = 0; i < 4; ++i) {
            int item = tid + i * 256, d = item & 127, sg = item >> 7;
            union { uint4 q; ushort_t u[8]; } tmp;
            #pragma unroll
            for (int j = 0; j < 8; ++j) tmp.u[j] = tile[sg * 8 + j][d];
            *(uint4*)(Vt + (((size_t)(b * 8 + e)) << 17) + (((size_t)d) << 10)
                      + s0 + (sg << 3)) = tmp.q;
        }
    }
}

// ---------------------------------------------------------------------------
// Kernel 2: attn_mega. Block = (16-row s-strip, b), 512 threads (8 waves).
// Unified 3-buffer rotating DMA pipeline with COUNTED vmcnt waits and
// raw s_barrier (no full VMEM drain per chunk — T3/T4).  Chunk sequence:
//   g in [0, ne*4)        : K chunks (32KB) of active experts
//   g in [ne*4, ne*4+16)  : V chunks (32KB), top-2 experts x 8
// Protocol per step g:
//   s_waitcnt vmcnt(4)   (only chunk g+1's 4 loads may remain per wave)
//   s_barrier            (all waves: chunk g fully landed in LDS)
//   sched_barrier(0)     (no LDS reads hoisted above the barrier)
//   issue chunk g+2      (buffer (g+2)%3 — its readers all passed this
//                         barrier, so reuse is race-free)
//   compute chunk g from buffer g%3
// Q tiles staged once up-front into qAll (uniform 1x4B load/thread each).
// ---------------------------------------------------------------------------
__global__ __launch_bounds__(512, 1) void attn_mega(
        const uchar* __restrict__ Qb, const uchar* __restrict__ Kb,
        const ushort_t* __restrict__ Vt, const float* __restrict__ route,
        const int* __restrict__ em, float* __restrict__ out) {

    __shared__ __align__(16) uchar kt3[3 * 32768];     // rotating chunk buffers
    __shared__ __align__(16) uchar qAll[16384];        // up to 8 Q tiles (2KB ea)
    __shared__ __align__(16) uchar attnL[32768];       // 16 x 1024 bf16, swizzled
    __shared__ float red[8][16];

    const int stile = blockIdx.x, b = blockIdx.y;
    const int s0 = stile * 16;
    const int tid = threadIdx.x;
    const int w = tid >> 6, lane = tid & 63;
    const int quad = lane >> 4, l16 = lane & 15;

    uint32 epack = 0; int ne = 0;
    #pragma unroll
    for (int e = 0; e < 8; ++e)
        if (em[e * B_ + b] != 0) { epack |= (uint32)e << (3 * ne); ++ne; }
    int i1, i2; top2(route + b * 8, i1, i2);

    const int tk = ne * 4;
    const int G = tk + 16;

    // t = c*256 + w*32 + n*16 + l16 ; rows quad*4+r
    f32x4 aacc[4][2];
    #pragma unroll
    for (int c = 0; c < 4; ++c)
        #pragma unroll
        for (int n = 0; n < 2; ++n) aacc[c][n] = (f32x4){0.f, 0.f, 0.f, 0.f};

    int ib = 0;   // next issue buffer
    int cb = 0;   // next compute buffer

    auto issue = [&](int g) {
        uchar* buf = kt3 + (size_t)ib * 32768u;
        if (g < tk) {
            int e = (epack >> (3 * (g >> 2))) & 7;
            stageK32(Kb + (((size_t)(b * 8 + e)) << 17) + (size_t)(g & 3) * 32768,
                     buf, tid);
        } else {
            int v = g - tk;
            int e = (v >> 3) ? i2 : i1;
            stageV32((const uchar*)(Vt + (((size_t)(b * 8 + e)) << 17))
                         + (size_t)(v & 7) * 256,
                     buf, tid);
        }
        ib = (ib == 2) ? 0 : ib + 1;
    };
    auto pipe = [&](int g) {
        if (g + 1 < G) asm volatile("s_waitcnt vmcnt(4)" ::: "memory");
        else           asm volatile("s_waitcnt vmcnt(0)" ::: "memory");
        __builtin_amdgcn_s_barrier();
        __builtin_amdgcn_sched_barrier(0);
        if (g + 2 < G) issue(g + 2);
    };

    // ---- prologue: all active-expert Q tiles, then chunks 0 and 1 ----
    for (int i = 0; i < ne; ++i) {
        int e = (epack >> (3 * i)) & 7;
        stageQ4(Qb + (((size_t)(b * 8 + e)) << 17) + ((size_t)s0 << 7),
                qAll + i * 2048, tid);
    }
    issue(0); issue(1);

    // ---- K phase: per active expert, 4 chunks + softmax-denominator ----
    for (int i = 0; i < ne; ++i) {
        const uchar* qp = qAll + i * 2048;
        u64 af[4];
        float rsum[4] = {0.f, 0.f, 0.f, 0.f};
        f32x4 ps[4][2];

        #pragma unroll
        for (int c = 0; c < 4; ++c) {
            int g = i * 4 + c;
            pipe(g);
            if (c == 0) {
                #pragma unroll
                for (int kk = 0; kk < 4; ++kk) af[kk] = fld8(qp, l16, kk, quad);
            }
            const uchar* kb = kt3 + (size_t)cb * 32768u;
            cb = (cb == 2) ? 0 : cb + 1;
            #pragma unroll
            for (int n = 0; n < 2; ++n) {
                f32x4 s = {0.f, 0.f, 0.f, 0.f};
                int trow = w * 32 + n * 16 + l16;
                #pragma unroll
                for (int kk = 0; kk < 4; ++kk) {
                    u64 bf = fld8(kb, trow, kk, quad);
                    s = __builtin_amdgcn_mfma_f32_16x16x32_fp8_fp8(
                        (long)af[kk], (long)bf, s, 0, 0, 0);
                }
                #pragma unroll
                for (int r = 0; r < 4; ++r) {
                    float p = __expf(s[r] * SCALE_);
                    ps[c][n][r] = p;
                    rsum[r] += p;
                }
            }
        }

        #pragma unroll
        for (int off = 1; off < 16; off <<= 1)
            #pragma unroll
            for (int r = 0; r < 4; ++r) rsum[r] += __shfl_xor(rsum[r], off, 64);
        if (l16 == 0) {
            #pragma unroll
            for (int r = 0; r < 4; ++r) red[w][quad * 4 + r] = rsum[r];
        }
        // lgkmcnt-only barrier: K/V DMA prefetches stay in flight across it
        asm volatile("s_waitcnt lgkmcnt(0)" ::: "memory");
        __builtin_amdgcn_s_barrier();
        __builtin_amdgcn_sched_barrier(0);
        float rinv[4];
        #pragma unroll
        for (int r = 0; r < 4; ++r) {
            float l = 0.f;
            #pragma unroll
            for (int ww = 0; ww < 8; ++ww) l += red[ww][quad * 4 + r];
            rinv[r] = 1.0f / l;
        }
        #pragma unroll
        for (int c = 0; c < 4; ++c)
            #pragma unroll
            for (int n = 0; n < 2; ++n)
                #pragma unroll
                for (int r = 0; r < 4; ++r)
                    aacc[c][n][r] += ps[c][n][r] * rinv[r];
    }

    // ---- attn strip -> LDS bf16 (swizzled 16B chunks) ----
    #pragma unroll
    for (int c = 0; c < 4; ++c)
        #pragma unroll
        for (int n = 0; n < 2; ++n)
            #pragma unroll
            for (int r = 0; r < 4; ++r) {
                int row = quad * 4 + r;
                int t = c * 256 + w * 32 + n * 16 + l16;
                int ct = t >> 3;
                int phys = (ct & ~7) | ((ct & 7) ^ (row & 7));
                *(ushort_t*)(attnL + row * 2048 + (phys << 4) + ((t & 7) << 1)) =
                    f2bf(aacc[c][n][r]);
            }
    // attnL visibility only — V-chunk DMAs remain in flight
    asm volatile("s_waitcnt lgkmcnt(0)" ::: "memory");
    __builtin_amdgcn_s_barrier();
    __builtin_amdgcn_sched_barrier(0);

    // ---- PV: wave w owns d-span w*16; sel outer, 8 x 128-t chunks each ----
    int selE[2] = {i1, i2};
    f32x4 oacc[2];
    #pragma unroll
    for (int sel = 0; sel < 2; ++sel) oacc[sel] = (f32x4){0.f, 0.f, 0.f, 0.f};

    #pragma unroll
    for (int sel = 0; sel < 2; ++sel) {
        #pragma unroll
        for (int c = 0; c < 8; ++c) {
            int g = tk + sel * 8 + c;
            pipe(g);
            const uchar* vb = kt3 + (size_t)cb * 32768u;
            cb = (cb == 2) ? 0 : cb + 1;
            #pragma unroll
            for (int kk = 0; kk < 4; ++kk) {
                int ct = c * 16 + kk * 4 + quad;
                int phys = (ct & ~7) | ((ct & 7) ^ (l16 & 7));
                short8 afr = *(const short8*)(attnL + l16 * 2048 + (phys << 4));
                short8 bfr = fldv(vb, w * 16 + l16, kk, quad);
                oacc[sel] = __builtin_amdgcn_mfma_f32_16x16x32_bf16(
                    afr, bfr, oacc[sel], 0, 0, 0);
            }
        }
    }
    #pragma unroll
    for (int sel = 0; sel < 2; ++sel)
        #pragma unroll
        for (int r = 0; r < 4; ++r)
            out[(((size_t)(b * 1024 + s0 + quad * 4 + r)) << 10)
                + selE[sel] * 128 + w * 16 + l16] = oacc[sel][r];
}

// ---------------------------------------------------------------------------
extern "C" void kernel_launch(void* const* d_in, const int* in_sizes, int n_in,
                              void* d_out, int out_size, void* d_ws, size_t ws_size,
                              hipStream_t stream) {
    const float* Q     = (const float*)d_in[0];
    const float* K     = (const float*)d_in[1];
    const float* V     = (const float*)d_in[2];
    const float* route = (const float*)d_in[3];
    const int*   em    = (const int*)d_in[4];
    float* out = (float*)d_out;

    const size_t NB = (size_t)B_ * E_ * S_ * DE_;     // 4.19M elems
    uchar* Qb = (uchar*)d_ws;                         // fp8 planes (NB bytes)
    uchar* Kb = Qb + NB;
    ushort_t* Vt = (ushort_t*)(Kb + NB);              // bf16 (NB elems)

    dim3 gp(16, 8, 4);
    prep_kernel<<<gp, 256, 0, stream>>>(Q, K, V, route, em, Qb, Kb, Vt, out);
    dim3 gm(64, 4);
    attn_mega<<<gm, 512, 0, stream>>>(Qb, Kb, Vt, route, em, out);
}